// Round 5
// baseline (142.592 us; speedup 1.0000x reference)
//
#include <hip/hip_runtime.h>

#define N_CAND 8192
#define TILE   64                           // tile edge = wave width
#define NTILES (N_CAND / TILE)              // 128
#define NLIVE  (NTILES * (NTILES + 1) / 2)  // 8256 upper-triangle tiles
#define WPB    4                            // waves per block
#define NBLK   1024                         // 4 blocks/CU on 256 CUs
#define NWAVE  (NBLK * WPB)                 // 4096 waves: 2 tiles each + 64 chunked strays
#define REPS   6                            // R14 PROBE: repeat work 6x, scale by 1/6

// Broadcast one lane's float to all lanes via SGPR (v_readlane_b32).
__device__ __forceinline__ float readlane_f(float x, int lane) {
    return __int_as_float(__builtin_amdgcn_readlane(__float_as_int(x), lane));
}

// ---------------------------------------------------------------------------
// R14: MEASUREMENT ROUND. Identical structure/math to R13 (2 trans/pair,
// exp2 hoisted, rolled j-loop, chunked strays). Each wave executes its tile
// set REPS=6 times (opaque zero offset per rep defeats CSE), partial scaled
// by 1/6. Purpose:
//   T_pairs = (dur_R14 - dur_R13) / 5   -- exact kernel cost, and
//   the pairs dispatch (~6T) becomes the TOP profiled dispatch, exposing its
//   VALUBusy / OccupancyPercent / VGPR counters for the first time.
// Result differs from R13 only by ~1 ulp accumulation noise (threshold 6.5e-3).
// ---------------------------------------------------------------------------
__device__ __forceinline__ float tile_range_sum(const float* __restrict__ logits,
                                                const int*   __restrict__ rankings,
                                                int t, int lane, int j0, int j1)
{
    // invert t = bj*(bj+1)/2 + bi, 0 <= bi <= bj < NTILES  (wave-uniform)
    t = __builtin_amdgcn_readfirstlane(t);
    int bj = (int)((__builtin_sqrtf(8.0f * (float)t + 1.0f) - 1.0f) * 0.5f);
    while ((bj + 1) * (bj + 2) / 2 <= t) ++bj;   // guard fp rounding
    while (bj * (bj + 1) / 2 > t)       --bj;
    const int bi = t - bj * (bj + 1) / 2;

    const float LOG2E = 1.4426950408889634f;
    const float INF   = __builtin_inff();

    const float lis = logits[bi * TILE + lane] * LOG2E;
    const float ri  = (float)rankings[bi * TILE + lane];
    const float ljs = logits[bj * TILE + lane] * LOG2E;
    const float rjv = (float)rankings[bj * TILE + lane];

    // exp2 hoisted out of the pair loop
    const float Ei  = __builtin_amdgcn_exp2f(lis);
    const float Ejv = __builtin_amdgcn_exp2f(ljs);

    float accL0 = 0.0f, accL1 = 0.0f, accL2 = 0.0f, accL3 = 0.0f;
    float accW0 = 0.0f, accW1 = 0.0f, accW2 = 0.0f, accW3 = 0.0f;

    if (bi != bj) {
        #pragma unroll 1
        for (int jj = j0; jj < j1; jj += 4) {
            const float Ej0 = readlane_f(Ejv, jj    ), rj0 = readlane_f(rjv, jj    );
            const float Ej1 = readlane_f(Ejv, jj + 1), rj1 = readlane_f(rjv, jj + 1);
            const float Ej2 = readlane_f(Ejv, jj + 2), rj2 = readlane_f(rjv, jj + 2);
            const float Ej3 = readlane_f(Ejv, jj + 3), rj3 = readlane_f(rjv, jj + 3);

            const float L0 = __builtin_amdgcn_logf(Ei + Ej0);
            const float L1 = __builtin_amdgcn_logf(Ei + Ej1);
            const float L2 = __builtin_amdgcn_logf(Ei + Ej2);
            const float L3 = __builtin_amdgcn_logf(Ei + Ej3);

            const float rs0 = (rj0 > ri) ? (ri + rj0) : INF;  // rcp(inf)=0 masks
            const float rs1 = (rj1 > ri) ? (ri + rj1) : INF;
            const float rs2 = (rj2 > ri) ? (ri + rj2) : INF;
            const float rs3 = (rj3 > ri) ? (ri + rj3) : INF;

            const float w0 = __builtin_amdgcn_rcpf(rs0);
            const float w1 = __builtin_amdgcn_rcpf(rs1);
            const float w2 = __builtin_amdgcn_rcpf(rs2);
            const float w3 = __builtin_amdgcn_rcpf(rs3);

            accL0 = fmaf(w0, L0, accL0);  accW0 += w0;
            accL1 = fmaf(w1, L1, accL1);  accW1 += w1;
            accL2 = fmaf(w2, L2, accL2);  accW2 += w2;
            accL3 = fmaf(w3, L3, accL3);  accW3 += w3;
        }
    } else {
        #pragma unroll 1
        for (int jj = j0; jj < j1; jj += 4) {
            const float Ej0 = readlane_f(Ejv, jj    ), rj0 = readlane_f(rjv, jj    );
            const float Ej1 = readlane_f(Ejv, jj + 1), rj1 = readlane_f(rjv, jj + 1);
            const float Ej2 = readlane_f(Ejv, jj + 2), rj2 = readlane_f(rjv, jj + 2);
            const float Ej3 = readlane_f(Ejv, jj + 3), rj3 = readlane_f(rjv, jj + 3);

            const float L0 = __builtin_amdgcn_logf(Ei + Ej0);
            const float L1 = __builtin_amdgcn_logf(Ei + Ej1);
            const float L2 = __builtin_amdgcn_logf(Ei + Ej2);
            const float L3 = __builtin_amdgcn_logf(Ei + Ej3);

            const float rs0 = ((jj     > lane) && (rj0 > ri)) ? (ri + rj0) : INF;
            const float rs1 = ((jj + 1 > lane) && (rj1 > ri)) ? (ri + rj1) : INF;
            const float rs2 = ((jj + 2 > lane) && (rj2 > ri)) ? (ri + rj2) : INF;
            const float rs3 = ((jj + 3 > lane) && (rj3 > ri)) ? (ri + rj3) : INF;

            const float w0 = __builtin_amdgcn_rcpf(rs0);
            const float w1 = __builtin_amdgcn_rcpf(rs1);
            const float w2 = __builtin_amdgcn_rcpf(rs2);
            const float w3 = __builtin_amdgcn_rcpf(rs3);

            accL0 = fmaf(w0, L0, accL0);  accW0 += w0;
            accL1 = fmaf(w1, L1, accL1);  accW1 += w1;
            accL2 = fmaf(w2, L2, accL2);  accW2 += w2;
            accL3 = fmaf(w3, L3, accL3);  accW3 += w3;
        }
    }

    const float accL = (accL0 + accL1) + (accL2 + accL3);
    const float accW = (accW0 + accW1) + (accW2 + accW3);
    return fmaf(-lis, accW, accL);   // factored -lis term, per lane
}

__global__ __launch_bounds__(256, 4) void ranknet_pairs_kernel(
    const float* __restrict__ logits,
    const int*   __restrict__ rankings,
    float*       __restrict__ partials)   // NBLK floats
{
    const int lane = threadIdx.x & 63;
    const int wave = threadIdx.x >> 6;
    const int gw   = __builtin_amdgcn_readfirstlane((int)blockIdx.x * WPB + wave);

    float lacc = 0.0f;
    #pragma unroll 1
    for (int rep = 0; rep < REPS; ++rep) {
        // opaque zero: compiler cannot prove reps identical -> no CSE across reps
        int off0 = 0;
        asm volatile("" : "+v"(off0));
        const float* lg = logits   + off0;
        const int*   rk = rankings + off0;

        // k=0: tile gw; k=1: tile gw+4096; k=2: stray 16-col chunk if owned.
        #pragma unroll 1
        for (int k = 0; k < 3; ++k) {
            int tt, jj0, jj1;
            bool live = true;
            if (k == 0)      { tt = gw;          jj0 = 0; jj1 = TILE; }
            else if (k == 1) { tt = gw + NWAVE;  jj0 = 0; jj1 = TILE; }
            else {
                const int c = gw >> 4;                    // chunk id, c < 256
                live = ((gw & 15) == (c & 3));            // wave 16c+(c&3) owns chunk c
                tt   = 2 * NWAVE + (c >> 2);              // stray tile 8192 + c/4
                jj0  = (c & 3) * 16;                      // 16-column chunk
                jj1  = jj0 + 16;
            }
            if (live) lacc += tile_range_sum(lg, rk, tt, lane, jj0, jj1);
        }
    }

    // wave reduce — no LDS
    #pragma unroll
    for (int off = 32; off > 0; off >>= 1)
        lacc += __shfl_down(lacc, off, 64);

    __shared__ float s_w[WPB];
    if (lane == 0) s_w[wave] = lacc;
    __syncthreads();
    if (threadIdx.x == 0)
        partials[blockIdx.x] = ((s_w[0] + s_w[1]) + (s_w[2] + s_w[3])) * (1.0f / (float)REPS);
}

// ---------------------------------------------------------------------------
// Pass 2: one 1024-thread block reduces the NBLK=1024 partials; applies ln2/N.
// ---------------------------------------------------------------------------
__global__ __launch_bounds__(1024) void ranknet_reduce_kernel(
    const float* __restrict__ partials,
    float*       __restrict__ out)
{
    __shared__ float s_part[16];
    const int tid = threadIdx.x;

    float acc = partials[tid];   // exactly 1024 partials

    #pragma unroll
    for (int off = 32; off > 0; off >>= 1)
        acc += __shfl_down(acc, off, 64);
    if ((tid & 63) == 0) s_part[tid >> 6] = acc;
    __syncthreads();
    if (tid == 0) {
        float s = 0.0f;
        #pragma unroll
        for (int w = 0; w < 16; ++w) s += s_part[w];
        const float LN2 = 0.6931471805599453f;
        out[0] = s * (LN2 / (float)N_CAND);
    }
}

extern "C" void kernel_launch(void* const* d_in, const int* in_sizes, int n_in,
                              void* d_out, int out_size, void* d_ws, size_t ws_size,
                              hipStream_t stream)
{
    const float* logits   = (const float*)d_in[0];
    const int*   rankings = (const int*)  d_in[1];
    float*       out      = (float*)d_out;
    float*       partials = (float*)d_ws;   // NBLK floats = 4 KB

    ranknet_pairs_kernel<<<dim3(NBLK), dim3(256), 0, stream>>>(logits, rankings, partials);
    ranknet_reduce_kernel<<<1, 1024, 0, stream>>>(partials, out);
}

// Round 6
// 68.806 us; speedup vs baseline: 2.0724x; 2.0724x over previous
//
#include <hip/hip_runtime.h>

#define N_CAND 8192
#define TILE   64                           // tile edge = wave width
#define NTILES (N_CAND / TILE)              // 128
#define NLIVE  (NTILES * (NTILES + 1) / 2)  // 8256 upper-triangle tiles
#define WPB    16                           // waves per block (1024 threads)
#define NBLK   256                          // 1 block/CU, 16 waves/CU
#define NWAVE  (NBLK * WPB)                 // 4096 waves: 2 tiles each + 64 chunked strays

// ---------------------------------------------------------------------------
// R15: issue-cycle attack, guided by the R14 probe (289 cy / 4-pair iter,
// VALUBusy 75%, trans = 16 cy issue each).
//  - rcp trans (16cy) -> integer-magic + 2 Newton steps (6 VALU = 12cy,
//    rel err ~7e-6; masked pairs may produce inf/NaN which cndmask discards).
//  - readlane j-broadcast (8 VALU + SGPR hazards) -> per-wave LDS stage,
//    wave-uniform ds_read (broadcast, conflict-free, LDS pipe not VALU port).
//    Same-wave RAW through LDS: no barrier.
//  - reduce kernel fused: one device-scope atomicAdd(out) per block (out is
//    zeroed by the harness memset before launch). 1024-thr blocks x 256.
// Budget: 44 VALU(88cy) + 4 log(64cy) = 152cy / 4-pair iter (was 289).
// ---------------------------------------------------------------------------

// 1/x via integer magic seed + 2 Newton iterations. ~7e-6 rel err for normal x.
__device__ __forceinline__ float fast_rcp(float x) {
    float y = __int_as_float(0x7EF311C3 - __float_as_int(x));
    y = y * fmaf(-x, y, 2.0f);
    y = y * fmaf(-x, y, 2.0f);
    return y;
}

__device__ __forceinline__ float tile_range_sum(
    const float* __restrict__ logits, const int* __restrict__ rankings,
    float* __restrict__ sEj, int* __restrict__ srj,
    int t, int lane, int j0, int j1)
{
    // invert t = bj*(bj+1)/2 + bi, 0 <= bi <= bj < NTILES  (wave-uniform)
    t = __builtin_amdgcn_readfirstlane(t);
    int bj = (int)((__builtin_sqrtf(8.0f * (float)t + 1.0f) - 1.0f) * 0.5f);
    while ((bj + 1) * (bj + 2) / 2 <= t) ++bj;   // guard fp rounding
    while (bj * (bj + 1) / 2 > t)       --bj;
    const int bi = t - bj * (bj + 1) / 2;

    const float LOG2E = 1.4426950408889634f;

    const float lis = logits[bi * TILE + lane] * LOG2E;
    const int   ri  = rankings[bi * TILE + lane];
    const float ljs = logits[bj * TILE + lane] * LOG2E;
    const int   rj  = rankings[bj * TILE + lane];

    // exp2 hoisted: E = 2^(l*log2e); log2(Ei+Ej) - lis == softplus(lj-li)/ln2
    const float Ei = __builtin_amdgcn_exp2f(lis);
    sEj[lane] = __builtin_amdgcn_exp2f(ljs);   // per-wave region; no barrier
    srj[lane] = rj;                            // (same-wave LDS RAW -> lgkmcnt)

    float accL0 = 0.0f, accL1 = 0.0f, accL2 = 0.0f, accL3 = 0.0f;
    float accW0 = 0.0f, accW1 = 0.0f, accW2 = 0.0f, accW3 = 0.0f;

    if (bi != bj) {
        #pragma unroll 1
        for (int jj = j0; jj < j1; jj += 4) {
            // wave-uniform LDS reads: broadcast, off the VALU issue port
            const float Ej0 = sEj[jj    ], Ej1 = sEj[jj + 1];
            const float Ej2 = sEj[jj + 2], Ej3 = sEj[jj + 3];
            const int   rj0 = srj[jj    ], rj1 = srj[jj + 1];
            const int   rj2 = srj[jj + 2], rj3 = srj[jj + 3];

            const float L0 = __builtin_amdgcn_logf(Ei + Ej0);
            const float L1 = __builtin_amdgcn_logf(Ei + Ej1);
            const float L2 = __builtin_amdgcn_logf(Ei + Ej2);
            const float L3 = __builtin_amdgcn_logf(Ei + Ej3);

            const float u0 = fast_rcp((float)(ri + rj0));
            const float u1 = fast_rcp((float)(ri + rj1));
            const float u2 = fast_rcp((float)(ri + rj2));
            const float u3 = fast_rcp((float)(ri + rj3));

            const float w0 = (rj0 > ri) ? u0 : 0.0f;   // masked inf/NaN discarded
            const float w1 = (rj1 > ri) ? u1 : 0.0f;
            const float w2 = (rj2 > ri) ? u2 : 0.0f;
            const float w3 = (rj3 > ri) ? u3 : 0.0f;

            accL0 = fmaf(w0, L0, accL0);  accW0 += w0;
            accL1 = fmaf(w1, L1, accL1);  accW1 += w1;
            accL2 = fmaf(w2, L2, accL2);  accW2 += w2;
            accL3 = fmaf(w3, L3, accL3);  accW3 += w3;
        }
    } else {
        // diagonal tile: also require j > i (jj > lane)
        #pragma unroll 1
        for (int jj = j0; jj < j1; jj += 4) {
            const float Ej0 = sEj[jj    ], Ej1 = sEj[jj + 1];
            const float Ej2 = sEj[jj + 2], Ej3 = sEj[jj + 3];
            const int   rj0 = srj[jj    ], rj1 = srj[jj + 1];
            const int   rj2 = srj[jj + 2], rj3 = srj[jj + 3];

            const float L0 = __builtin_amdgcn_logf(Ei + Ej0);
            const float L1 = __builtin_amdgcn_logf(Ei + Ej1);
            const float L2 = __builtin_amdgcn_logf(Ei + Ej2);
            const float L3 = __builtin_amdgcn_logf(Ei + Ej3);

            const float u0 = fast_rcp((float)(ri + rj0));
            const float u1 = fast_rcp((float)(ri + rj1));
            const float u2 = fast_rcp((float)(ri + rj2));
            const float u3 = fast_rcp((float)(ri + rj3));

            const float w0 = ((jj     > lane) && (rj0 > ri)) ? u0 : 0.0f;
            const float w1 = ((jj + 1 > lane) && (rj1 > ri)) ? u1 : 0.0f;
            const float w2 = ((jj + 2 > lane) && (rj2 > ri)) ? u2 : 0.0f;
            const float w3 = ((jj + 3 > lane) && (rj3 > ri)) ? u3 : 0.0f;

            accL0 = fmaf(w0, L0, accL0);  accW0 += w0;
            accL1 = fmaf(w1, L1, accL1);  accW1 += w1;
            accL2 = fmaf(w2, L2, accL2);  accW2 += w2;
            accL3 = fmaf(w3, L3, accL3);  accW3 += w3;
        }
    }

    const float accL = (accL0 + accL1) + (accL2 + accL3);
    const float accW = (accW0 + accW1) + (accW2 + accW3);
    return fmaf(-lis, accW, accL);   // factored -lis term, per lane
}

__global__ __launch_bounds__(1024, 4) void ranknet_fused_kernel(
    const float* __restrict__ logits,
    const int*   __restrict__ rankings,
    float*       __restrict__ out)
{
    __shared__ float s_Ej[WPB][TILE];   // 4 KB
    __shared__ int   s_rj[WPB][TILE];   // 4 KB
    __shared__ float s_w[WPB];

    const int tid  = threadIdx.x;
    const int lane = tid & 63;
    const int wave = tid >> 6;
    const int gw   = __builtin_amdgcn_readfirstlane((int)blockIdx.x * WPB + wave);

    float lacc = 0.0f;
    // k=0: tile gw; k=1: tile gw+4096; k=2: stray 16-col chunk if owned.
    #pragma unroll 1
    for (int k = 0; k < 3; ++k) {
        int tt, jj0, jj1;
        bool live = true;
        if (k == 0)      { tt = gw;          jj0 = 0; jj1 = TILE; }
        else if (k == 1) { tt = gw + NWAVE;  jj0 = 0; jj1 = TILE; }
        else {
            const int c = gw >> 4;                    // chunk id, c < 256
            live = ((gw & 15) == (c & 3));            // wave 16c+(c&3) owns chunk c
            tt   = 2 * NWAVE + (c >> 2);              // stray tile 8192 + c/4
            jj0  = (c & 3) * 16;                      // 16-column chunk
            jj1  = jj0 + 16;
        }
        if (live)
            lacc += tile_range_sum(logits, rankings, s_Ej[wave], s_rj[wave],
                                   tt, lane, jj0, jj1);
    }

    // wave reduce
    #pragma unroll
    for (int off = 32; off > 0; off >>= 1)
        lacc += __shfl_down(lacc, off, 64);
    if (lane == 0) s_w[wave] = lacc;
    __syncthreads();

    // block reduce + fused final accumulation (out[0] zeroed by harness memset)
    if (tid == 0) {
        float s = 0.0f;
        #pragma unroll
        for (int w = 0; w < WPB; ++w) s += s_w[w];
        const float LN2 = 0.6931471805599453f;
        atomicAdd(out, s * (LN2 / (float)N_CAND));
    }
}

extern "C" void kernel_launch(void* const* d_in, const int* in_sizes, int n_in,
                              void* d_out, int out_size, void* d_ws, size_t ws_size,
                              hipStream_t stream)
{
    const float* logits   = (const float*)d_in[0];
    const int*   rankings = (const int*)  d_in[1];
    float*       out      = (float*)d_out;
    (void)d_ws; (void)ws_size;

    ranknet_fused_kernel<<<dim3(NBLK), dim3(1024), 0, stream>>>(logits, rankings, out);
}

// Round 7
// 68.196 us; speedup vs baseline: 2.0909x; 1.0090x over previous
//
#include <hip/hip_runtime.h>
#include <hip/hip_fp16.h>

#define N_CAND 8192
#define TILE   64                           // tile edge = wave width
#define NTILES (N_CAND / TILE)              // 128
#define NLIVE  (NTILES * (NTILES + 1) / 2)  // 8256 upper-triangle tiles
#define WPB    16                           // waves per block (1024 threads)
#define NBLK   256                          // 1 block/CU
#define NWAVE  (NBLK * WPB)                 // 4096 waves: 2 tiles each + 64 chunked strays
#define RTAB   (2 * N_CAND)                 // 16384 rcp-table entries (ri+rj <= 16382)

// ---------------------------------------------------------------------------
// R16: minimum-issue inner loop. Ledger: R15 cut modeled issue 289->160cy/iter
// for only -1.6us; either LDS latency ate the gain or the envelope dominates.
// Both readings say: keep cutting issue cycles. Change vs R15:
//  - fast_rcp (6 VALU = 12cy/j) -> fp16 LDS table s_rcp[16384] (32KB), built
//    once per block. Per j: 1 ds_read_u16 (LDS pipe, not VALU port) + 1 cvt.
//    fp16 rel err 4.9e-4 -> loss err ~1.6e-4 << 6.5e-3 threshold; 1/16382 is
//    still fp16-normal (2^-14 = 6.1035e-5 < 6.1043e-5).
//  - everything else identical to R15 (per-wave Ej/rj LDS stage, wave-uniform
//    broadcast reads, rolled j-loop, chunked strays, fused atomicAdd).
// Per-j budget: ~7 VALU (14cy) + log (16cy) = 30cy -> ~124cy/4-pair iter.
// ---------------------------------------------------------------------------
__device__ __forceinline__ float tile_range_sum(
    const float* __restrict__ logits, const int* __restrict__ rankings,
    const __half* __restrict__ rcp_tab,
    float* __restrict__ sEj, int* __restrict__ srj,
    int t, int lane, int j0, int j1)
{
    // invert t = bj*(bj+1)/2 + bi, 0 <= bi <= bj < NTILES  (wave-uniform)
    t = __builtin_amdgcn_readfirstlane(t);
    int bj = (int)((__builtin_sqrtf(8.0f * (float)t + 1.0f) - 1.0f) * 0.5f);
    while ((bj + 1) * (bj + 2) / 2 <= t) ++bj;   // guard fp rounding
    while (bj * (bj + 1) / 2 > t)       --bj;
    const int bi = t - bj * (bj + 1) / 2;

    const float LOG2E = 1.4426950408889634f;

    const float lis = logits[bi * TILE + lane] * LOG2E;
    const int   ri  = rankings[bi * TILE + lane];
    const float ljs = logits[bj * TILE + lane] * LOG2E;
    const int   rj  = rankings[bj * TILE + lane];

    // exp2 hoisted: log2(Ei+Ej) - lis == softplus(lj-li)/ln2
    const float Ei = __builtin_amdgcn_exp2f(lis);
    sEj[lane] = __builtin_amdgcn_exp2f(ljs);   // per-wave region; same-wave RAW
    srj[lane] = rj;                            // -> lgkmcnt, no barrier

    // per-lane row base into the rcp table (hoists ri out of the loop)
    const __half* __restrict__ rowp = rcp_tab + ri;

    float accL0 = 0.0f, accL1 = 0.0f, accL2 = 0.0f, accL3 = 0.0f;
    float accW0 = 0.0f, accW1 = 0.0f, accW2 = 0.0f, accW3 = 0.0f;

    if (bi != bj) {
        #pragma unroll 1
        for (int jj = j0; jj < j1; jj += 4) {
            const float Ej0 = sEj[jj    ], Ej1 = sEj[jj + 1];
            const float Ej2 = sEj[jj + 2], Ej3 = sEj[jj + 3];
            const int   rj0 = srj[jj    ], rj1 = srj[jj + 1];
            const int   rj2 = srj[jj + 2], rj3 = srj[jj + 3];

            const float L0 = __builtin_amdgcn_logf(Ei + Ej0);
            const float L1 = __builtin_amdgcn_logf(Ei + Ej1);
            const float L2 = __builtin_amdgcn_logf(Ei + Ej2);
            const float L3 = __builtin_amdgcn_logf(Ei + Ej3);

            const float u0 = __half2float(rowp[rj0]);   // 1/(ri+rj) via LDS
            const float u1 = __half2float(rowp[rj1]);
            const float u2 = __half2float(rowp[rj2]);
            const float u3 = __half2float(rowp[rj3]);

            const float w0 = (rj0 > ri) ? u0 : 0.0f;    // masked inf discarded
            const float w1 = (rj1 > ri) ? u1 : 0.0f;
            const float w2 = (rj2 > ri) ? u2 : 0.0f;
            const float w3 = (rj3 > ri) ? u3 : 0.0f;

            accL0 = fmaf(w0, L0, accL0);  accW0 += w0;
            accL1 = fmaf(w1, L1, accL1);  accW1 += w1;
            accL2 = fmaf(w2, L2, accL2);  accW2 += w2;
            accL3 = fmaf(w3, L3, accL3);  accW3 += w3;
        }
    } else {
        // diagonal tile: also require j > i (jj > lane)
        #pragma unroll 1
        for (int jj = j0; jj < j1; jj += 4) {
            const float Ej0 = sEj[jj    ], Ej1 = sEj[jj + 1];
            const float Ej2 = sEj[jj + 2], Ej3 = sEj[jj + 3];
            const int   rj0 = srj[jj    ], rj1 = srj[jj + 1];
            const int   rj2 = srj[jj + 2], rj3 = srj[jj + 3];

            const float L0 = __builtin_amdgcn_logf(Ei + Ej0);
            const float L1 = __builtin_amdgcn_logf(Ei + Ej1);
            const float L2 = __builtin_amdgcn_logf(Ei + Ej2);
            const float L3 = __builtin_amdgcn_logf(Ei + Ej3);

            const float u0 = __half2float(rowp[rj0]);
            const float u1 = __half2float(rowp[rj1]);
            const float u2 = __half2float(rowp[rj2]);
            const float u3 = __half2float(rowp[rj3]);

            const float w0 = ((jj     > lane) && (rj0 > ri)) ? u0 : 0.0f;
            const float w1 = ((jj + 1 > lane) && (rj1 > ri)) ? u1 : 0.0f;
            const float w2 = ((jj + 2 > lane) && (rj2 > ri)) ? u2 : 0.0f;
            const float w3 = ((jj + 3 > lane) && (rj3 > ri)) ? u3 : 0.0f;

            accL0 = fmaf(w0, L0, accL0);  accW0 += w0;
            accL1 = fmaf(w1, L1, accL1);  accW1 += w1;
            accL2 = fmaf(w2, L2, accL2);  accW2 += w2;
            accL3 = fmaf(w3, L3, accL3);  accW3 += w3;
        }
    }

    const float accL = (accL0 + accL1) + (accL2 + accL3);
    const float accW = (accW0 + accW1) + (accW2 + accW3);
    return fmaf(-lis, accW, accL);   // factored -lis term, per lane
}

__global__ __launch_bounds__(1024, 4) void ranknet_fused_kernel(
    const float* __restrict__ logits,
    const int*   __restrict__ rankings,
    float*       __restrict__ out)
{
    __shared__ __half s_rcp[RTAB];      // 32 KB fp16 reciprocal table
    __shared__ float  s_Ej[WPB][TILE];  // 4 KB
    __shared__ int    s_rj[WPB][TILE];  // 4 KB
    __shared__ float  s_w[WPB];

    const int tid  = threadIdx.x;
    const int lane = tid & 63;
    const int wave = tid >> 6;
    const int gw   = __builtin_amdgcn_readfirstlane((int)blockIdx.x * WPB + wave);

    // build rcp table: 16 entries per thread; entry 0 = inf (always masked)
    #pragma unroll
    for (int k = 0; k < RTAB / 1024; ++k) {
        const int idx = tid + k * 1024;
        s_rcp[idx] = __float2half(__builtin_amdgcn_rcpf((float)idx));
    }
    __syncthreads();

    float lacc = 0.0f;
    // k=0: tile gw; k=1: tile gw+4096; k=2: stray 16-col chunk if owned.
    #pragma unroll 1
    for (int k = 0; k < 3; ++k) {
        int tt, jj0, jj1;
        bool live = true;
        if (k == 0)      { tt = gw;          jj0 = 0; jj1 = TILE; }
        else if (k == 1) { tt = gw + NWAVE;  jj0 = 0; jj1 = TILE; }
        else {
            const int c = gw >> 4;                    // chunk id, c < 256
            live = ((gw & 15) == (c & 3));            // wave 16c+(c&3) owns chunk c
            tt   = 2 * NWAVE + (c >> 2);              // stray tile 8192 + c/4
            jj0  = (c & 3) * 16;                      // 16-column chunk
            jj1  = jj0 + 16;
        }
        if (live)
            lacc += tile_range_sum(logits, rankings, s_rcp,
                                   s_Ej[wave], s_rj[wave], tt, lane, jj0, jj1);
    }

    // wave reduce
    #pragma unroll
    for (int off = 32; off > 0; off >>= 1)
        lacc += __shfl_down(lacc, off, 64);
    if (lane == 0) s_w[wave] = lacc;
    __syncthreads();

    // block reduce + fused final accumulation (out[0] zeroed by harness memset)
    if (tid == 0) {
        float s = 0.0f;
        #pragma unroll
        for (int w = 0; w < WPB; ++w) s += s_w[w];
        const float LN2 = 0.6931471805599453f;
        atomicAdd(out, s * (LN2 / (float)N_CAND));
    }
}

extern "C" void kernel_launch(void* const* d_in, const int* in_sizes, int n_in,
                              void* d_out, int out_size, void* d_ws, size_t ws_size,
                              hipStream_t stream)
{
    const float* logits   = (const float*)d_in[0];
    const int*   rankings = (const int*)  d_in[1];
    float*       out      = (float*)d_out;
    (void)d_ws; (void)ws_size;

    ranknet_fused_kernel<<<dim3(NBLK), dim3(1024), 0, stream>>>(logits, rankings, out);
}